// Round 9
// baseline (1093.219 us; speedup 1.0000x reference)
//
#include <hip/hip_runtime.h>
#include <hip/hip_fp16.h>
#include <cstdint>
#include <cstddef>

// ---------------------------------------------------------------------------
// helpers
// ---------------------------------------------------------------------------
typedef _Float16 hh2   __attribute__((ext_vector_type(2)));
typedef _Float16 f16x8 __attribute__((ext_vector_type(8)));
typedef float    f32x4 __attribute__((ext_vector_type(4)));
typedef int      i32x4 __attribute__((ext_vector_type(4)));
typedef int      v2i   __attribute__((ext_vector_type(2)));

__device__ __forceinline__ float fdot2u(unsigned a, unsigned b, float c) {
#if __has_builtin(__builtin_amdgcn_fdot2)
    return __builtin_amdgcn_fdot2(__builtin_bit_cast(hh2, a),
                                  __builtin_bit_cast(hh2, b), c, false);
#else
    float r;
    asm("v_dot2_f32_f16 %0, %1, %2, %3" : "=v"(r) : "v"(a), "v"(b), "v"(c));
    return r;
#endif
}

__device__ __forceinline__ unsigned packh2f(float x, float y) {
    hh2 v; v.x = (_Float16)x; v.y = (_Float16)y;
    return __builtin_bit_cast(unsigned, v);
}

__device__ __forceinline__ float ex2(float x) {
#if __has_builtin(__builtin_amdgcn_exp2f)
    return __builtin_amdgcn_exp2f(x);
#else
    return exp2f(x);
#endif
}
__device__ __forceinline__ float sig2(float x) {
    return __builtin_amdgcn_rcpf(1.f + ex2(x * -1.442695041f));
}
__device__ __forceinline__ float tanh2(float x) {
    return fmaf(2.f, __builtin_amdgcn_rcpf(1.f + ex2(x * -2.885390082f)), -1.f);
}
__device__ __forceinline__ float sigmoidf_fast(float x) {
    return __builtin_amdgcn_rcpf(1.f + __expf(-x));
}
__device__ __forceinline__ float tanhf_fast(float x) {
    float e = __expf(-2.f * fmaxf(x, -30.f));
    return (1.f - e) * __builtin_amdgcn_rcpf(1.f + e);
}

// raw barrier: drain LDS only, keep global loads in flight
#define BAR_LGKM() asm volatile("s_waitcnt lgkmcnt(0)\n\ts_barrier" ::: "memory")

// ---------------------------------------------------------------------------
// Kernel A: xpT = f16(x @ W + b) in chunked-transposed layout:
//   xpT[(row/8)][col][row%8]   (each [c8][col] cell = 8 halves = 16B)
// ---------------------------------------------------------------------------
__global__ __launch_bounds__(512, 2)
void k_xprojT(const float* __restrict__ x, const float* __restrict__ W,
              const float* __restrict__ bias, __half* __restrict__ xpT,
              int B, int T)
{
    __shared__ unsigned short xst[2][16 * 64];

    const int tid = threadIdx.x;
    const int w   = tid >> 6;
    const int l   = tid & 63;
    const int lj  = l & 15;
    const int hi  = l >> 4;
    const int bb  = blockIdx.x >> 2;
    const int q   = blockIdx.x & 3;

    f16x8 Wf[4][2];
    float bc[4];
#pragma unroll
    for (int cg = 0; cg < 4; ++cg) {
        const int col = cg * 128 + w * 16 + lj;
#pragma unroll
        for (int kk = 0; kk < 2; ++kk)
#pragma unroll
            for (int j = 0; j < 8; ++j)
                Wf[cg][kk][j] = (_Float16)W[(size_t)(kk*32 + hi*8 + j) * 512 + col];
        bc[cg] = bias[col];
    }

    const int nch = (T / 4) / 16;
    const size_t rowbase = (size_t)bb * T + (size_t)q * (T / 4);

    const int srow = tid >> 5;
    const int scp  = tid & 31;

    float2 xn = *(const float2*)(x + (rowbase + srow) * 64 + scp * 2);

    for (int ch = 0; ch < nch; ++ch) {
        unsigned pk = packh2f(xn.x, xn.y);
        *(unsigned*)((char*)xst[ch & 1] +
            (((srow * 128 + scp * 4)) ^ ((srow & 7) << 4))) = pk;
        if (ch + 1 < nch)
            xn = *(const float2*)(x + (rowbase + (ch+1)*16 + srow) * 64 + scp * 2);
        BAR_LGKM();

        f16x8 Axf[2];
#pragma unroll
        for (int kk = 0; kk < 2; ++kk)
            Axf[kk] = *(const f16x8*)((char*)xst[ch & 1] +
                ((lj * 128 + kk * 64 + hi * 16) ^ ((lj & 7) << 4)));

        const size_t c8base = (rowbase + (size_t)ch * 16) >> 3;
#pragma unroll
        for (int cg = 0; cg < 4; ++cg) {
            f32x4 C = {bc[cg], bc[cg], bc[cg], bc[cg]};
            C = __builtin_amdgcn_mfma_f32_16x16x32_f16(Axf[0], Wf[cg][0], C, 0, 0, 0);
            C = __builtin_amdgcn_mfma_f32_16x16x32_f16(Axf[1], Wf[cg][1], C, 0, 0, 0);
            const int col = cg * 128 + w * 16 + lj;
            uint2 u;
            u.x = packh2f(C[0], C[1]);
            u.y = packh2f(C[2], C[3]);
            const size_t hidx = ((c8base + (hi >> 1)) * 512 + col) * 8 + (hi & 1) * 4;
            *(uint2*)((unsigned short*)xpT + hidx) = u;
        }
        BAR_LGKM();
    }
}

// ---------------------------------------------------------------------------
// Kernel B: PAIRED i8-MFMA LSTM. One block = TWO batches, 1024 threads
// (16 waves). bat=(w^(w>>2))&1 guarantees each SIMD hosts 2 waves of each
// batch under either wave->SIMD convention -> one batch's VALU/stall phase
// hides under the other's MFMA burst (m114 co-schedule). cg = w>>1.
// Quarter->gate map {i,g,f,o}: lane-exchange is 1 ds_swizzle(xor16)
// (i*g in lower half, f&o in upper half) + 1 permlane32_swap (carry p=i*g
// to upper half, which owns c/h) -- no LDS exchange round-trip.
// Per step/wave: 2 ds_read_b128 + 8 i8-MFMA + ~45 VALU + 1 barrier.
// ---------------------------------------------------------------------------
__global__ __launch_bounds__(1024, 4)
void k_lstm9(const float* __restrict__ U, const __half* __restrict__ xpT,
             __half* __restrict__ hs, int T)
{
    __shared__ unsigned char hbuf[2][2][128];   // [bat][dbuf][col], 512 B

    const int tid = threadIdx.x;
    const int w   = tid >> 6;                   // 0..15
    const int l   = tid & 63;
    const int lj  = l & 15;
    const int hi  = l >> 4;
    const int bat = (w ^ (w >> 2)) & 1;         // 2+2 mix per SIMD
    const int cg  = w >> 1;                     // 0..7 col-group in batch
    const int bb  = blockIdx.x * 2 + bat;

    // quarter -> gate map {i,g,f,o} = {0,2,1,3}
    const int g_me = (hi == 1) ? 2 : (hi == 2) ? 1 : hi;

    // ---- one-time U quantization: per-column i8 B-frags (all 4 gates)
    i32x4 Bq[4][2];
    float um[4];
#pragma unroll
    for (int g = 0; g < 4; ++g) {
        const int col = g * 128 + cg * 16 + lj;
        float m = 0.f;
        for (int k2 = 0; k2 < 128; ++k2)
            m = fmaxf(m, fabsf(U[(size_t)k2 * 512 + col]));
        um[g] = m;
        const float s = (m > 0.f) ? 127.f / m : 0.f;
#pragma unroll
        for (int kk = 0; kk < 2; ++kk) {
            int wds[4];
#pragma unroll
            for (int d = 0; d < 4; ++d) {
                unsigned word = 0;
#pragma unroll
                for (int b = 0; b < 4; ++b) {
                    int qv = (int)rintf(
                        U[(size_t)(kk*64 + hi*16 + d*4 + b) * 512 + col] * s);
                    word |= (unsigned)(qv & 255) << (8 * b);
                }
                wds[d] = (int)word;
            }
            Bq[g][kk] = (i32x4){wds[0], wds[1], wds[2], wds[3]};
        }
    }

    // per-lane gate constants for MY gate
    const float um_me = (hi == 1) ? um[2] : (hi == 2) ? um[1]
                      : (hi == 3) ? um[3] : um[0];
    const float dq_me = um_me * (1.f / (127.f * 127.f));
    const float mlt = (hi == 1) ? -2.885390082f : -1.442695041f;  // g=tanh
    const float pa  = (hi == 1) ? 2.f : 1.f;
    const float pb  = (hi == 1) ? -1.f : 0.f;

    if (tid < 128) ((unsigned*)hbuf)[tid] = 0u;   // zero all h buffers

    // xp prefetch: my (gate,col), one 16B cell per 8 steps
    const uint4* __restrict__ xb = (const uint4*)xpT;
    const size_t xrow = (size_t)bb * (T / 8) * 512;
    const int col_me = g_me * 128 + cg * 16 + lj;

    uint4 qA = xb[xrow + 0 * 512 + col_me];
    uint4 qB = xb[xrow + 1 * 512 + col_me];

    __half* __restrict__ hsb = hs + (size_t)bb * T * 128;
    float cst = 0.f;

    // persistent accumulators; elem 0 reseeded per step, elems 1-3 garbage
    i32x4 Cq[4] = {{0,0,0,0},{0,0,0,0},{0,0,0,0},{0,0,0,0}};

    __syncthreads();

    const int nbody = T / 16;
    for (int k = 0; k < nbody; ++k) {
#pragma unroll
        for (int p = 0; p < 16; ++p) {
            if (p == 8)
                qA = xb[xrow + (size_t)(2*k + 2) * 512 + col_me];

            // A-frags (i8, row-broadcast): quarter hi reads its 16B k-slice
            const unsigned char* hrow = &hbuf[bat][p & 1][0];
            i32x4 Aq0 = *(const i32x4*)(hrow + hi * 16);
            i32x4 Aq1 = *(const i32x4*)(hrow + 64 + hi * 16);

            Cq[0][0] = 0; Cq[1][0] = 0; Cq[2][0] = 0; Cq[3][0] = 0;
#pragma unroll
            for (int g = 0; g < 4; ++g) {
                Cq[g] = __builtin_amdgcn_mfma_i32_16x16x64_i8(Aq0, Bq[g][0], Cq[g], 0, 0, 0);
                Cq[g] = __builtin_amdgcn_mfma_i32_16x16x64_i8(Aq1, Bq[g][1], Cq[g], 0, 0, 0);
            }

            // select MY gate's z: hi0->Cq0(i), hi1->Cq2(g), hi2->Cq1(f), hi3->Cq3(o)
            int a01 = (hi & 1) ? Cq[2][0] : Cq[0][0];
            int a23 = (hi & 1) ? Cq[3][0] : Cq[1][0];
            int zi  = (hi & 2) ? a23 : a01;

            // xp value for my (gate,col)
            const uint4 qq = (p < 8) ? qA : qB;
            const int wsel = (p & 7) >> 1;
            unsigned uw = (wsel == 0) ? qq.x : (wsel == 1) ? qq.y
                        : (wsel == 2) ? qq.z : qq.w;
            __half2 hh = __builtin_bit_cast(__half2, uw);
            float xpf = __half2float((p & 1) ? __high2half(hh) : __low2half(hh));

            float zf = fmaf((float)zi, dq_me, xpf);

            // unified activation (tanh for quarter 1, sigmoid otherwise)
            float e = ex2(zf * mlt);
            float a = fmaf(pa, __builtin_amdgcn_rcpf(1.f + e), pb);

            // within-half exchange: q0<->q1 (i<->g), q2<->q3 (f<->o)
            float s1 = __builtin_bit_cast(float,
                __builtin_amdgcn_ds_swizzle(__builtin_bit_cast(int, a), 0x401F));

            float pv = a * s1;                       // i*g (valid lower half)
            float fv = (hi == 2) ? a : s1;           // f (valid upper half)
            float ov = (hi == 2) ? s1 : a;           // o (valid upper half)

            // cross-half: carry p = i*g into upper half (VALU permlane)
#if __has_builtin(__builtin_amdgcn_permlane32_swap)
            v2i r = __builtin_amdgcn_permlane32_swap(
                __builtin_bit_cast(int, pv), __builtin_bit_cast(int, pv),
                false, false);
            float pc = __builtin_bit_cast(float, r[0]);  // upper: partner's p
#else
            __shared__ float pex[16][16];
            if (hi == 0) pex[w][lj] = pv;
            asm volatile("s_waitcnt lgkmcnt(0)" ::: "memory");
            float pc = pex[w][lj];
#endif

            cst = fmaf(fv, cst, pc);                 // c = f*c + i*g  (upper)
            float h = ov * tanh2(cst);               // h = o*tanh(c)  (upper)

            if (hi == 2) {                           // 16 lanes per wave
                hbuf[bat][(p & 1) ^ 1][cg * 16 + lj] =
                    (unsigned char)(int)rintf(h * 127.f);
                hsb[(size_t)(k * 16 + p) * 128 + cg * 16 + lj] = __float2half(h);
            }

            if (p == 15)
                qB = xb[xrow + (size_t)(2*k + 3) * 512 + col_me];
            BAR_LGKM();
        }
    }
}

// ---------------------------------------------------------------------------
// Kernel C: dense head, wide (256 CUs). Block = (batch, chunk-group of 4).
// ---------------------------------------------------------------------------
__global__ __launch_bounds__(512, 2)
void k_head(const __half* __restrict__ hs,
            const float* __restrict__ W1, const float* __restrict__ b1,
            const float* __restrict__ W2, const float* __restrict__ b2,
            const float* __restrict__ W3, const float* __restrict__ b3,
            const float* __restrict__ W4, const float* __restrict__ b4,
            float* __restrict__ out, int T)
{
    __shared__ unsigned short hstage[16 * 128];
    __shared__ unsigned short d1buf[16 * 128];
    __shared__ unsigned short d2buf[16 * 128];
    __shared__ unsigned short d3buf[16 * 40];

    const int tid = threadIdx.x;
    const int w   = tid >> 6;
    const int l   = tid & 63;
    const int lj  = l & 15;
    const int hi  = l >> 4;
    const int bb  = blockIdx.x >> 5;
    const int ch0 = (blockIdx.x & 31) * 4;

    const int col1 = w * 16 + lj;
    const int col3 = (w & 1) * 16 + lj;

    f16x8 W1f[4], W2f[4], W3f[4];
#pragma unroll
    for (int kk = 0; kk < 4; ++kk)
#pragma unroll
        for (int j = 0; j < 8; ++j) {
            W1f[kk][j] = (_Float16)W1[(size_t)(kk*32 + hi*8 + j) * 128 + col1];
            W2f[kk][j] = (_Float16)W2[(size_t)(kk*32 + hi*8 + j) * 128 + col1];
            W3f[kk][j] = (_Float16)W3[(size_t)(kk*32 + hi*8 + j) * 32 + col3];
        }
    const float b1c = b1[col1];
    const float b2c = b2[col1];
    const float b3c = b3[col3];
    unsigned w4p[16];
#pragma unroll
    for (int k2 = 0; k2 < 16; ++k2)
        w4p[k2] = packh2f(W4[2*k2], W4[2*k2 + 1]);
    const float b4v = b4[0];

    const __half* __restrict__ hsb = hs + (size_t)bb * T * 128;
    const int srow = tid >> 5;
    const int scp  = tid & 31;

    for (int ch = ch0; ch < ch0 + 4; ++ch) {
        const int t0 = ch * 16;
        uint2 hv = *(const uint2*)(hsb + (size_t)(t0 + srow) * 128 + scp * 4);
        *(uint2*)((char*)hstage + ((srow * 256 + scp * 8) ^ ((srow & 7) << 4))) = hv;
        __syncthreads();

        f16x8 A[4];
#pragma unroll
        for (int kk = 0; kk < 4; ++kk)
            A[kk] = *(const f16x8*)((char*)hstage +
                ((lj * 256 + kk * 64 + hi * 16) ^ ((lj & 7) << 4)));
        f32x4 C1 = {b1c, b1c, b1c, b1c};
#pragma unroll
        for (int kk = 0; kk < 4; ++kk)
            C1 = __builtin_amdgcn_mfma_f32_16x16x32_f16(A[kk], W1f[kk], C1, 0, 0, 0);
#pragma unroll
        for (int r = 0; r < 4; ++r) {
            const int row = hi * 4 + r;
            *(unsigned short*)((char*)d1buf + ((row * 256 + col1 * 2) ^ ((row & 7) << 4))) =
                __half_as_ushort(__float2half(C1[r]));
        }
        __syncthreads();

#pragma unroll
        for (int kk = 0; kk < 4; ++kk)
            A[kk] = *(const f16x8*)((char*)d1buf +
                ((lj * 256 + kk * 64 + hi * 16) ^ ((lj & 7) << 4)));
        f32x4 C2 = {b2c, b2c, b2c, b2c};
#pragma unroll
        for (int kk = 0; kk < 4; ++kk)
            C2 = __builtin_amdgcn_mfma_f32_16x16x32_f16(A[kk], W2f[kk], C2, 0, 0, 0);
#pragma unroll
        for (int r = 0; r < 4; ++r) {
            const int row = hi * 4 + r;
            *(unsigned short*)((char*)d2buf + ((row * 256 + col1 * 2) ^ ((row & 7) << 4))) =
                __half_as_ushort(__float2half(fmaxf(C2[r], 0.f)));
        }
        __syncthreads();

#pragma unroll
        for (int kk = 0; kk < 4; ++kk)
            A[kk] = *(const f16x8*)((char*)d2buf +
                ((lj * 256 + kk * 64 + hi * 16) ^ ((lj & 7) << 4)));
        f32x4 C3 = {b3c, b3c, b3c, b3c};
#pragma unroll
        for (int kk = 0; kk < 4; ++kk)
            C3 = __builtin_amdgcn_mfma_f32_16x16x32_f16(A[kk], W3f[kk], C3, 0, 0, 0);
        if (w < 2) {
#pragma unroll
            for (int r = 0; r < 4; ++r) {
                const int row = hi * 4 + r;
                d3buf[row * 40 + col3] =
                    __half_as_ushort(__float2half(fmaxf(C3[r], 0.f)));
            }
        }
        __syncthreads();

        if (w == 0 && l < 16) {
            const unsigned short* dr = &d3buf[l * 40];
            float s0 = b4v, s1 = 0.f;
#pragma unroll
            for (int qq = 0; qq < 4; ++qq) {
                uint4 v = *(const uint4*)(dr + qq * 8);
                s0 = fdot2u(v.x, w4p[qq*4 + 0], s0);
                s1 = fdot2u(v.y, w4p[qq*4 + 1], s1);
                s0 = fdot2u(v.z, w4p[qq*4 + 2], s0);
                s1 = fdot2u(v.w, w4p[qq*4 + 3], s1);
            }
            out[(size_t)bb * T + t0 + l] = sigmoidf_fast(s0 + s1);
        }
        __syncthreads();
    }
}

// ---------------------------------------------------------------------------
// Fallback path (small workspace): round-1 fused dot2 LSTM + dot2 head.
// ---------------------------------------------------------------------------
__global__ __launch_bounds__(512)
void k_lstm_fused(const float* __restrict__ U, const float* __restrict__ x,
                  const float* __restrict__ W, const float* __restrict__ bias,
                  __half* __restrict__ hs, int T)
{
    __shared__ __align__(16) unsigned hbuf[64];
    __shared__ float act[512];
    __shared__ __align__(16) unsigned xrow[32];

    const int g    = threadIdx.x;
    const int bb   = blockIdx.x;
    const int j    = g & 127;
    const int gate = g >> 7;

    unsigned ucol[64];
#pragma unroll
    for (int k2 = 0; k2 < 64; ++k2)
        ucol[k2] = packh2f(U[(2*k2)*512 + g], U[(2*k2+1)*512 + g]);
    unsigned wcol[32];
#pragma unroll
    for (int k2 = 0; k2 < 32; ++k2)
        wcol[k2] = packh2f(W[(2*k2)*512 + g], W[(2*k2+1)*512 + g]);
    const float bg = bias[g];
    const float2* __restrict__ xb2 = (const float2*)(x + (size_t)bb * T * 64);
    if (g < 32) { float2 x0 = xb2[g]; xrow[g] = packh2f(x0.x, x0.y); }
    if (g < 64) hbuf[g] = 0u;
    float c = 0.f;
    __half* __restrict__ hsb = hs + (size_t)bb * T * 128;
    __syncthreads();

    for (int t = 0; t < T; ++t) {
        float2 xn = make_float2(0.f, 0.f);
        if (g < 32 && t + 1 < T) xn = xb2[(size_t)(t + 1) * 32 + g];
        float a0 = bg, a1 = 0.f, a2 = 0.f, a3 = 0.f;
        const uint4* hr = (const uint4*)hbuf;
#pragma unroll
        for (int k8 = 0; k8 < 16; ++k8) {
            uint4 v = hr[k8];
            a0 = fdot2u(v.x, ucol[4*k8+0], a0);
            a1 = fdot2u(v.y, ucol[4*k8+1], a1);
            a2 = fdot2u(v.z, ucol[4*k8+2], a2);
            a3 = fdot2u(v.w, ucol[4*k8+3], a3);
        }
        const uint4* xr = (const uint4*)xrow;
#pragma unroll
        for (int k8 = 0; k8 < 8; ++k8) {
            uint4 v = xr[k8];
            a0 = fdot2u(v.x, wcol[4*k8+0], a0);
            a1 = fdot2u(v.y, wcol[4*k8+1], a1);
            a2 = fdot2u(v.z, wcol[4*k8+2], a2);
            a3 = fdot2u(v.w, wcol[4*k8+3], a3);
        }
        float z = (a0 + a1) + (a2 + a3);
        float a = (gate == 2) ? tanhf_fast(z) : sigmoidf_fast(z);
        act[g] = a;
        __syncthreads();
        float iv = act[j], fv = act[j + 128], gv = act[j + 256], ov = act[j + 384];
        c = fmaf(fv, c, iv * gv);
        float h = ov * tanhf_fast(c);
        if (gate == 0) {
            ((unsigned short*)hbuf)[j] = __half_as_ushort(__float2half(h));
            hsb[(size_t)t * 128 + j] = __float2half(h);
        }
        if (g < 32 && t + 1 < T) xrow[g] = packh2f(xn.x, xn.y);
        __syncthreads();
    }
}

template<bool RELU>
__global__ __launch_bounds__(512)
void k_fc128(const __half* __restrict__ in16, const float* __restrict__ Wg,
             const float* __restrict__ bias, __half* __restrict__ out16, int rows)
{
    __shared__ __align__(16) unsigned rowbuf[4 * 64];
    const int tid = threadIdx.x;
    const int n   = tid & 127;
    const int rs  = tid >> 7;
    unsigned wcol[64];
#pragma unroll
    for (int k2 = 0; k2 < 64; ++k2)
        wcol[k2] = packh2f(Wg[(2*k2)*128 + n], Wg[(2*k2+1)*128 + n]);
    const float bn = bias[n];
    for (int row0 = blockIdx.x * 4; row0 < rows; row0 += gridDim.x * 4) {
        if (tid < 256)
            rowbuf[tid] = ((const unsigned*)(in16 + (size_t)row0 * 128))[tid];
        __syncthreads();
        float a0 = bn, a1 = 0.f, a2 = 0.f, a3 = 0.f;
        const uint4* hr = (const uint4*)(rowbuf + rs * 64);
#pragma unroll
        for (int k8 = 0; k8 < 16; ++k8) {
            uint4 v = hr[k8];
            a0 = fdot2u(v.x, wcol[4*k8+0], a0);
            a1 = fdot2u(v.y, wcol[4*k8+1], a1);
            a2 = fdot2u(v.z, wcol[4*k8+2], a2);
            a3 = fdot2u(v.w, wcol[4*k8+3], a3);
        }
        float a = (a0 + a1) + (a2 + a3);
        if (RELU) a = fmaxf(a, 0.f);
        out16[(size_t)(row0 + rs) * 128 + n] = __float2half(a);
        __syncthreads();
    }
}

__global__ __launch_bounds__(512)
void k_l34(const __half* __restrict__ in16, const float* __restrict__ W3,
           const float* __restrict__ b3, const float* __restrict__ W4,
           const float* __restrict__ b4, float* __restrict__ out, int rows)
{
    __shared__ __align__(16) unsigned rowbuf[16 * 64];
    __shared__ __align__(16) unsigned short d3s[16 * 32];
    const int tid = threadIdx.x;
    const int n   = tid & 31;
    const int rs  = tid >> 5;
    unsigned w3col[64];
#pragma unroll
    for (int k2 = 0; k2 < 64; ++k2)
        w3col[k2] = packh2f(W3[(2*k2)*32 + n], W3[(2*k2+1)*32 + n]);
    unsigned w4p[16];
#pragma unroll
    for (int k2 = 0; k2 < 16; ++k2)
        w4p[k2] = packh2f(W4[2*k2], W4[2*k2+1]);
    const float b3n = b3[n], b4v = b4[0];
    for (int row0 = blockIdx.x * 16; row0 < rows; row0 += gridDim.x * 16) {
        rowbuf[tid]       = ((const unsigned*)(in16 + (size_t)row0 * 128))[tid];
        rowbuf[tid + 512] = ((const unsigned*)(in16 + (size_t)row0 * 128))[tid + 512];
        __syncthreads();
        float a0 = b3n, a1 = 0.f, a2 = 0.f, a3 = 0.f;
        const uint4* hr = (const uint4*)(rowbuf + rs * 64);
#pragma unroll
        for (int k8 = 0; k8 < 16; ++k8) {
            uint4 v = hr[k8];
            a0 = fdot2u(v.x, w3col[4*k8+0], a0);
            a1 = fdot2u(v.y, w3col[4*k8+1], a1);
            a2 = fdot2u(v.z, w3col[4*k8+2], a2);
            a3 = fdot2u(v.w, w3col[4*k8+3], a3);
        }
        float a = fmaxf((a0 + a1) + (a2 + a3), 0.f);
        d3s[rs * 32 + n] = __half_as_ushort(__float2half(a));
        __syncthreads();
        if (tid < 16) {
            const uint4* dp = (const uint4*)(d3s + tid * 32);
            float s0 = b4v, s1 = 0.f;
#pragma unroll
            for (int qq = 0; qq < 4; ++qq) {
                uint4 v = dp[qq];
                s0 = fdot2u(v.x, w4p[4*qq+0], s0);
                s1 = fdot2u(v.y, w4p[4*qq+1], s1);
                s0 = fdot2u(v.z, w4p[4*qq+2], s0);
                s1 = fdot2u(v.w, w4p[4*qq+3], s1);
            }
            out[row0 + tid] = sigmoidf_fast(s0 + s1);
        }
        __syncthreads();
    }
}

// ---------------------------------------------------------------------------
extern "C" void kernel_launch(void* const* d_in, const int* in_sizes, int n_in,
                              void* d_out, int out_size, void* d_ws, size_t ws_size,
                              hipStream_t stream)
{
    const float* x  = (const float*)d_in[0];
    const float* W  = (const float*)d_in[1];
    const float* U  = (const float*)d_in[2];
    const float* b  = (const float*)d_in[3];
    const float* W1 = (const float*)d_in[4];
    const float* b1 = (const float*)d_in[5];
    const float* W2 = (const float*)d_in[6];
    const float* b2 = (const float*)d_in[7];
    const float* W3 = (const float*)d_in[8];
    const float* b3 = (const float*)d_in[9];
    const float* W4 = (const float*)d_in[10];
    const float* b4 = (const float*)d_in[11];
    float* out = (float*)d_out;

    const int T    = 2048;
    const int rows = in_sizes[0] / 64;     // B*T
    const int B    = rows / T;             // 64

    char* ws = (char*)d_ws;
    const size_t xp_bytes = (size_t)rows * 512 * sizeof(__half);   // 128 MiB
    const size_t hs_bytes = (size_t)rows * 128 * sizeof(__half);   //  32 MiB

    if (ws_size >= xp_bytes + hs_bytes && (B & 1) == 0) {
        __half* xpT  = (__half*)ws;
        __half* hs16 = (__half*)(ws + xp_bytes);
        k_xprojT<<<B * 4, 512, 0, stream>>>(x, W, b, xpT, B, T);
        k_lstm9<<<B / 2, 1024, 0, stream>>>(U, xpT, hs16, T);
        k_head<<<B * 32, 512, 0, stream>>>(hs16, W1, b1, W2, b2, W3, b3,
                                           W4, b4, out, T);
    } else {
        __half* hs16 = (__half*)ws;
        __half* d1   = (__half*)(ws + hs_bytes);
        __half* d2   = (__half*)ws;   // alias hs (dead after fc1)
        k_lstm_fused<<<B, 512, 0, stream>>>(U, x, W, b, hs16, T);
        k_fc128<false><<<1024, 512, 0, stream>>>(hs16, W1, b1, d1, rows);
        k_fc128<true ><<<1024, 512, 0, stream>>>(d1,  W2, b2, d2, rows);
        k_l34<<<1024, 512, 0, stream>>>(d2, W3, b3, W4, b4, out, rows);
    }
}

// Round 10
// 841.425 us; speedup vs baseline: 1.2992x; 1.2992x over previous
//
#include <hip/hip_runtime.h>
#include <hip/hip_fp16.h>
#include <cstdint>
#include <cstddef>

// ---------------------------------------------------------------------------
// helpers
// ---------------------------------------------------------------------------
typedef _Float16 hh2   __attribute__((ext_vector_type(2)));
typedef _Float16 f16x8 __attribute__((ext_vector_type(8)));
typedef float    f32x4 __attribute__((ext_vector_type(4)));
typedef int      i32x4 __attribute__((ext_vector_type(4)));
typedef int      v2i   __attribute__((ext_vector_type(2)));

__device__ __forceinline__ float fdot2u(unsigned a, unsigned b, float c) {
#if __has_builtin(__builtin_amdgcn_fdot2)
    return __builtin_amdgcn_fdot2(__builtin_bit_cast(hh2, a),
                                  __builtin_bit_cast(hh2, b), c, false);
#else
    float r;
    asm("v_dot2_f32_f16 %0, %1, %2, %3" : "=v"(r) : "v"(a), "v"(b), "v"(c));
    return r;
#endif
}

__device__ __forceinline__ unsigned packh2f(float x, float y) {
    hh2 v; v.x = (_Float16)x; v.y = (_Float16)y;
    return __builtin_bit_cast(unsigned, v);
}

__device__ __forceinline__ float ex2(float x) {
#if __has_builtin(__builtin_amdgcn_exp2f)
    return __builtin_amdgcn_exp2f(x);
#else
    return exp2f(x);
#endif
}
__device__ __forceinline__ float sig2(float x) {
    return __builtin_amdgcn_rcpf(1.f + ex2(x * -1.442695041f));
}
__device__ __forceinline__ float tanh2(float x) {
    return fmaf(2.f, __builtin_amdgcn_rcpf(1.f + ex2(x * -2.885390082f)), -1.f);
}
__device__ __forceinline__ float sigmoidf_fast(float x) {
    return __builtin_amdgcn_rcpf(1.f + __expf(-x));
}
__device__ __forceinline__ float tanhf_fast(float x) {
    float e = __expf(-2.f * fmaxf(x, -30.f));
    return (1.f - e) * __builtin_amdgcn_rcpf(1.f + e);
}

// raw barrier: drain LDS only, keep global loads in flight
#define BAR_LGKM() asm volatile("s_waitcnt lgkmcnt(0)\n\ts_barrier" ::: "memory")

// ---------------------------------------------------------------------------
// Kernel A: xpT = f16(x @ W + b) in chunked-transposed layout:
//   xpT[(row/8)][col][row%8]   (each [c8][col] cell = 8 halves = 16B)
// ---------------------------------------------------------------------------
__global__ __launch_bounds__(512, 2)
void k_xprojT(const float* __restrict__ x, const float* __restrict__ W,
              const float* __restrict__ bias, __half* __restrict__ xpT,
              int B, int T)
{
    __shared__ unsigned short xst[2][16 * 64];

    const int tid = threadIdx.x;
    const int w   = tid >> 6;
    const int l   = tid & 63;
    const int lj  = l & 15;
    const int hi  = l >> 4;
    const int bb  = blockIdx.x >> 2;
    const int q   = blockIdx.x & 3;

    f16x8 Wf[4][2];
    float bc[4];
#pragma unroll
    for (int cg = 0; cg < 4; ++cg) {
        const int col = cg * 128 + w * 16 + lj;
#pragma unroll
        for (int kk = 0; kk < 2; ++kk)
#pragma unroll
            for (int j = 0; j < 8; ++j)
                Wf[cg][kk][j] = (_Float16)W[(size_t)(kk*32 + hi*8 + j) * 512 + col];
        bc[cg] = bias[col];
    }

    const int nch = (T / 4) / 16;
    const size_t rowbase = (size_t)bb * T + (size_t)q * (T / 4);

    const int srow = tid >> 5;
    const int scp  = tid & 31;

    float2 xn = *(const float2*)(x + (rowbase + srow) * 64 + scp * 2);

    for (int ch = 0; ch < nch; ++ch) {
        unsigned pk = packh2f(xn.x, xn.y);
        *(unsigned*)((char*)xst[ch & 1] +
            (((srow * 128 + scp * 4)) ^ ((srow & 7) << 4))) = pk;
        if (ch + 1 < nch)
            xn = *(const float2*)(x + (rowbase + (ch+1)*16 + srow) * 64 + scp * 2);
        BAR_LGKM();

        f16x8 Axf[2];
#pragma unroll
        for (int kk = 0; kk < 2; ++kk)
            Axf[kk] = *(const f16x8*)((char*)xst[ch & 1] +
                ((lj * 128 + kk * 64 + hi * 16) ^ ((lj & 7) << 4)));

        const size_t c8base = (rowbase + (size_t)ch * 16) >> 3;
#pragma unroll
        for (int cg = 0; cg < 4; ++cg) {
            f32x4 C = {bc[cg], bc[cg], bc[cg], bc[cg]};
            C = __builtin_amdgcn_mfma_f32_16x16x32_f16(Axf[0], Wf[cg][0], C, 0, 0, 0);
            C = __builtin_amdgcn_mfma_f32_16x16x32_f16(Axf[1], Wf[cg][1], C, 0, 0, 0);
            const int col = cg * 128 + w * 16 + lj;
            uint2 u;
            u.x = packh2f(C[0], C[1]);
            u.y = packh2f(C[2], C[3]);
            const size_t hidx = ((c8base + (hi >> 1)) * 512 + col) * 8 + (hi & 1) * 4;
            *(uint2*)((unsigned short*)xpT + hidx) = u;
        }
        BAR_LGKM();
    }
}

// ---------------------------------------------------------------------------
// Kernel B: i8-MFMA LSTM, single batch/block (r8 geometry) + r9's verified
// swizzle/permlane exchange (no LDS round-trip, no bank conflicts) + chain-
// shadow scheduling: ds_reads issue first after the barrier; the previous
// step's hs store (register-carried), xp extract and Cq zeroing run under
// the ~120cyc LDS read latency. Quarter->gate map {i,g,f,o}.
// Per step/wave: 2 ds_read_b128 + 8 i8-MFMA + ~40 VALU + swizzle/permlane +
// 1 ds_write_b8 + 1 barrier.
// ---------------------------------------------------------------------------
__global__ __launch_bounds__(512, 2)
void k_lstm10(const float* __restrict__ U, const __half* __restrict__ xpT,
              __half* __restrict__ hs, int T)
{
    __shared__ unsigned char hbuf[2][128];      // h as i8, double-buffered

    const int tid = threadIdx.x;
    const int w   = tid >> 6;                   // 0..7 (col group)
    const int l   = tid & 63;
    const int lj  = l & 15;
    const int hi  = l >> 4;
    const int bb  = blockIdx.x;

    // quarter -> gate map {i,g,f,o} = {0,2,1,3}
    const int g_me = (hi == 1) ? 2 : (hi == 2) ? 1 : hi;

    // ---- one-time U quantization: per-column i8 B-frags (all 4 gates)
    i32x4 Bq[4][2];
    float um[4];
#pragma unroll
    for (int g = 0; g < 4; ++g) {
        const int col = g * 128 + w * 16 + lj;
        float m = 0.f;
        for (int k2 = 0; k2 < 128; ++k2)
            m = fmaxf(m, fabsf(U[(size_t)k2 * 512 + col]));
        um[g] = m;
        const float s = (m > 0.f) ? 127.f / m : 0.f;
#pragma unroll
        for (int kk = 0; kk < 2; ++kk) {
            int wds[4];
#pragma unroll
            for (int d = 0; d < 4; ++d) {
                unsigned word = 0;
#pragma unroll
                for (int b = 0; b < 4; ++b) {
                    int qv = (int)rintf(
                        U[(size_t)(kk*64 + hi*16 + d*4 + b) * 512 + col] * s);
                    word |= (unsigned)(qv & 255) << (8 * b);
                }
                wds[d] = (int)word;
            }
            Bq[g][kk] = (i32x4){wds[0], wds[1], wds[2], wds[3]};
        }
    }

    // per-lane gate constants for MY gate
    const float um_me = (hi == 1) ? um[2] : (hi == 2) ? um[1]
                      : (hi == 3) ? um[3] : um[0];
    const float dq_me = um_me * (1.f / (127.f * 127.f));
    const float mlt = (hi == 1) ? -2.885390082f : -1.442695041f;  // g=tanh
    const float pa  = (hi == 1) ? 2.f : 1.f;
    const float pb  = (hi == 1) ? -1.f : 0.f;

    if (tid < 32) ((unsigned*)hbuf[0])[tid] = 0u;   // zero initial h (buf 0)

    // xp prefetch: my (gate,col), one 16B cell per 8 steps
    const uint4* __restrict__ xb = (const uint4*)xpT;
    const size_t xrow = (size_t)bb * (T / 8) * 512;
    const int col_me = g_me * 128 + w * 16 + lj;

    uint4 qA = xb[xrow + 0 * 512 + col_me];
    uint4 qB = xb[xrow + 1 * 512 + col_me];

    __half* __restrict__ hsb = hs + (size_t)bb * T * 128;
    float cst = 0.f;
    float h_prev = 0.f;

    // persistent accumulators; elem 0 zeroed per step, elems 1-3 garbage
    i32x4 Cq[4] = {{0,0,0,0},{0,0,0,0},{0,0,0,0},{0,0,0,0}};

    __syncthreads();

    const int nbody = T / 16;
    for (int k = 0; k < nbody; ++k) {
#pragma unroll
        for (int p = 0; p < 16; ++p) {
            // ---- reads first: A-frags for this step (fills the shadow)
            const unsigned char* hrow = &hbuf[p & 1][0];
            i32x4 Aq0 = *(const i32x4*)(hrow + hi * 16);
            i32x4 Aq1 = *(const i32x4*)(hrow + 64 + hi * 16);

            // ---- shadow work: previous step's hs store (independent)
            if ((k > 0 || p > 0) && hi == 2)
                hsb[(size_t)(k * 16 + p - 1) * 128 + w * 16 + lj] =
                    __float2half(h_prev);

            if (p == 8)
                qA = xb[xrow + (size_t)(2*k + 2) * 512 + col_me];

            // ---- shadow work: xp extract for this step (static selects)
            const uint4 qq = (p < 8) ? qA : qB;
            const int wsel = (p & 7) >> 1;
            unsigned uw = (wsel == 0) ? qq.x : (wsel == 1) ? qq.y
                        : (wsel == 2) ? qq.z : qq.w;
            __half2 hh = __builtin_bit_cast(__half2, uw);
            float xpf = __half2float((p & 1) ? __high2half(hh) : __low2half(hh));

            Cq[0][0] = 0; Cq[1][0] = 0; Cq[2][0] = 0; Cq[3][0] = 0;
#pragma unroll
            for (int g = 0; g < 4; ++g) {
                Cq[g] = __builtin_amdgcn_mfma_i32_16x16x64_i8(Aq0, Bq[g][0], Cq[g], 0, 0, 0);
                Cq[g] = __builtin_amdgcn_mfma_i32_16x16x64_i8(Aq1, Bq[g][1], Cq[g], 0, 0, 0);
            }

            // select MY gate's z: hi0->Cq0(i), hi1->Cq2(g), hi2->Cq1(f), hi3->Cq3(o)
            int a01 = (hi & 1) ? Cq[2][0] : Cq[0][0];
            int a23 = (hi & 1) ? Cq[3][0] : Cq[1][0];
            int zi  = (hi & 2) ? a23 : a01;

            float zf = fmaf((float)zi, dq_me, xpf);

            // unified activation (tanh for quarter 1, sigmoid otherwise)
            float e = ex2(zf * mlt);
            float a = fmaf(pa, __builtin_amdgcn_rcpf(1.f + e), pb);

            // within-half exchange: q0<->q1 (i<->g), q2<->q3 (f<->o)
            float s1 = __builtin_bit_cast(float,
                __builtin_amdgcn_ds_swizzle(__builtin_bit_cast(int, a), 0x401F));

            float pv = a * s1;                       // i*g (valid lower half)
            float fv = (hi == 2) ? a : s1;           // f (valid upper half)
            float ov = (hi == 2) ? s1 : a;           // o (valid upper half)

            // cross-half: carry p = i*g into upper half (VALU permlane)
#if __has_builtin(__builtin_amdgcn_permlane32_swap)
            v2i r = __builtin_amdgcn_permlane32_swap(
                __builtin_bit_cast(int, pv), __builtin_bit_cast(int, pv),
                false, false);
            float pc = __builtin_bit_cast(float, r[0]);  // upper: partner's p
#else
            __shared__ float pex[8][16];
            if (hi == 0) pex[w][lj] = pv;
            asm volatile("s_waitcnt lgkmcnt(0)" ::: "memory");
            float pc = pex[w][lj];
#endif

            cst = fmaf(fv, cst, pc);                 // c = f*c + i*g  (upper)
            float h = ov * tanh2(cst);               // h = o*tanh(c)  (upper)
            h_prev = h;

            if (hi == 2)                             // 16 lanes per wave
                hbuf[(p & 1) ^ 1][w * 16 + lj] =
                    (unsigned char)(int)rintf(h * 127.f);

            if (p == 15)
                qB = xb[xrow + (size_t)(2*k + 3) * 512 + col_me];
            BAR_LGKM();
        }
    }
    // tail: final step's hs store
    if (hi == 2)
        hsb[(size_t)(T - 1) * 128 + w * 16 + lj] = __float2half(h_prev);
}

// ---------------------------------------------------------------------------
// Kernel C: dense head, wide (256 CUs). Block = (batch, chunk-group of 4).
// ---------------------------------------------------------------------------
__global__ __launch_bounds__(512, 2)
void k_head(const __half* __restrict__ hs,
            const float* __restrict__ W1, const float* __restrict__ b1,
            const float* __restrict__ W2, const float* __restrict__ b2,
            const float* __restrict__ W3, const float* __restrict__ b3,
            const float* __restrict__ W4, const float* __restrict__ b4,
            float* __restrict__ out, int T)
{
    __shared__ unsigned short hstage[16 * 128];
    __shared__ unsigned short d1buf[16 * 128];
    __shared__ unsigned short d2buf[16 * 128];
    __shared__ unsigned short d3buf[16 * 40];

    const int tid = threadIdx.x;
    const int w   = tid >> 6;
    const int l   = tid & 63;
    const int lj  = l & 15;
    const int hi  = l >> 4;
    const int bb  = blockIdx.x >> 5;
    const int ch0 = (blockIdx.x & 31) * 4;

    const int col1 = w * 16 + lj;
    const int col3 = (w & 1) * 16 + lj;

    f16x8 W1f[4], W2f[4], W3f[4];
#pragma unroll
    for (int kk = 0; kk < 4; ++kk)
#pragma unroll
        for (int j = 0; j < 8; ++j) {
            W1f[kk][j] = (_Float16)W1[(size_t)(kk*32 + hi*8 + j) * 128 + col1];
            W2f[kk][j] = (_Float16)W2[(size_t)(kk*32 + hi*8 + j) * 128 + col1];
            W3f[kk][j] = (_Float16)W3[(size_t)(kk*32 + hi*8 + j) * 32 + col3];
        }
    const float b1c = b1[col1];
    const float b2c = b2[col1];
    const float b3c = b3[col3];
    unsigned w4p[16];
#pragma unroll
    for (int k2 = 0; k2 < 16; ++k2)
        w4p[k2] = packh2f(W4[2*k2], W4[2*k2 + 1]);
    const float b4v = b4[0];

    const __half* __restrict__ hsb = hs + (size_t)bb * T * 128;
    const int srow = tid >> 5;
    const int scp  = tid & 31;

    for (int ch = ch0; ch < ch0 + 4; ++ch) {
        const int t0 = ch * 16;
        uint2 hv = *(const uint2*)(hsb + (size_t)(t0 + srow) * 128 + scp * 4);
        *(uint2*)((char*)hstage + ((srow * 256 + scp * 8) ^ ((srow & 7) << 4))) = hv;
        __syncthreads();

        f16x8 A[4];
#pragma unroll
        for (int kk = 0; kk < 4; ++kk)
            A[kk] = *(const f16x8*)((char*)hstage +
                ((lj * 256 + kk * 64 + hi * 16) ^ ((lj & 7) << 4)));
        f32x4 C1 = {b1c, b1c, b1c, b1c};
#pragma unroll
        for (int kk = 0; kk < 4; ++kk)
            C1 = __builtin_amdgcn_mfma_f32_16x16x32_f16(A[kk], W1f[kk], C1, 0, 0, 0);
#pragma unroll
        for (int r = 0; r < 4; ++r) {
            const int row = hi * 4 + r;
            *(unsigned short*)((char*)d1buf + ((row * 256 + col1 * 2) ^ ((row & 7) << 4))) =
                __half_as_ushort(__float2half(C1[r]));
        }
        __syncthreads();

#pragma unroll
        for (int kk = 0; kk < 4; ++kk)
            A[kk] = *(const f16x8*)((char*)d1buf +
                ((lj * 256 + kk * 64 + hi * 16) ^ ((lj & 7) << 4)));
        f32x4 C2 = {b2c, b2c, b2c, b2c};
#pragma unroll
        for (int kk = 0; kk < 4; ++kk)
            C2 = __builtin_amdgcn_mfma_f32_16x16x32_f16(A[kk], W2f[kk], C2, 0, 0, 0);
#pragma unroll
        for (int r = 0; r < 4; ++r) {
            const int row = hi * 4 + r;
            *(unsigned short*)((char*)d2buf + ((row * 256 + col1 * 2) ^ ((row & 7) << 4))) =
                __half_as_ushort(__float2half(fmaxf(C2[r], 0.f)));
        }
        __syncthreads();

#pragma unroll
        for (int kk = 0; kk < 4; ++kk)
            A[kk] = *(const f16x8*)((char*)d2buf +
                ((lj * 256 + kk * 64 + hi * 16) ^ ((lj & 7) << 4)));
        f32x4 C3 = {b3c, b3c, b3c, b3c};
#pragma unroll
        for (int kk = 0; kk < 4; ++kk)
            C3 = __builtin_amdgcn_mfma_f32_16x16x32_f16(A[kk], W3f[kk], C3, 0, 0, 0);
        if (w < 2) {
#pragma unroll
            for (int r = 0; r < 4; ++r) {
                const int row = hi * 4 + r;
                d3buf[row * 40 + col3] =
                    __half_as_ushort(__float2half(fmaxf(C3[r], 0.f)));
            }
        }
        __syncthreads();

        if (w == 0 && l < 16) {
            const unsigned short* dr = &d3buf[l * 40];
            float s0 = b4v, s1 = 0.f;
#pragma unroll
            for (int qq = 0; qq < 4; ++qq) {
                uint4 v = *(const uint4*)(dr + qq * 8);
                s0 = fdot2u(v.x, w4p[qq*4 + 0], s0);
                s1 = fdot2u(v.y, w4p[qq*4 + 1], s1);
                s0 = fdot2u(v.z, w4p[qq*4 + 2], s0);
                s1 = fdot2u(v.w, w4p[qq*4 + 3], s1);
            }
            out[(size_t)bb * T + t0 + l] = sigmoidf_fast(s0 + s1);
        }
        __syncthreads();
    }
}

// ---------------------------------------------------------------------------
// Fallback path (small workspace): round-1 fused dot2 LSTM + dot2 head.
// ---------------------------------------------------------------------------
__global__ __launch_bounds__(512)
void k_lstm_fused(const float* __restrict__ U, const float* __restrict__ x,
                  const float* __restrict__ W, const float* __restrict__ bias,
                  __half* __restrict__ hs, int T)
{
    __shared__ __align__(16) unsigned hbuf[64];
    __shared__ float act[512];
    __shared__ __align__(16) unsigned xrow[32];

    const int g    = threadIdx.x;
    const int bb   = blockIdx.x;
    const int j    = g & 127;
    const int gate = g >> 7;

    unsigned ucol[64];
#pragma unroll
    for (int k2 = 0; k2 < 64; ++k2)
        ucol[k2] = packh2f(U[(2*k2)*512 + g], U[(2*k2+1)*512 + g]);
    unsigned wcol[32];
#pragma unroll
    for (int k2 = 0; k2 < 32; ++k2)
        wcol[k2] = packh2f(W[(2*k2)*512 + g], W[(2*k2+1)*512 + g]);
    const float bg = bias[g];
    const float2* __restrict__ xb2 = (const float2*)(x + (size_t)bb * T * 64);
    if (g < 32) { float2 x0 = xb2[g]; xrow[g] = packh2f(x0.x, x0.y); }
    if (g < 64) hbuf[g] = 0u;
    float c = 0.f;
    __half* __restrict__ hsb = hs + (size_t)bb * T * 128;
    __syncthreads();

    for (int t = 0; t < T; ++t) {
        float2 xn = make_float2(0.f, 0.f);
        if (g < 32 && t + 1 < T) xn = xb2[(size_t)(t + 1) * 32 + g];
        float a0 = bg, a1 = 0.f, a2 = 0.f, a3 = 0.f;
        const uint4* hr = (const uint4*)hbuf;
#pragma unroll
        for (int k8 = 0; k8 < 16; ++k8) {
            uint4 v = hr[k8];
            a0 = fdot2u(v.x, ucol[4*k8+0], a0);
            a1 = fdot2u(v.y, ucol[4*k8+1], a1);
            a2 = fdot2u(v.z, ucol[4*k8+2], a2);
            a3 = fdot2u(v.w, ucol[4*k8+3], a3);
        }
        const uint4* xr = (const uint4*)xrow;
#pragma unroll
        for (int k8 = 0; k8 < 8; ++k8) {
            uint4 v = xr[k8];
            a0 = fdot2u(v.x, wcol[4*k8+0], a0);
            a1 = fdot2u(v.y, wcol[4*k8+1], a1);
            a2 = fdot2u(v.z, wcol[4*k8+2], a2);
            a3 = fdot2u(v.w, wcol[4*k8+3], a3);
        }
        float z = (a0 + a1) + (a2 + a3);
        float a = (gate == 2) ? tanhf_fast(z) : sigmoidf_fast(z);
        act[g] = a;
        __syncthreads();
        float iv = act[j], fv = act[j + 128], gv = act[j + 256], ov = act[j + 384];
        c = fmaf(fv, c, iv * gv);
        float h = ov * tanhf_fast(c);
        if (gate == 0) {
            ((unsigned short*)hbuf)[j] = __half_as_ushort(__float2half(h));
            hsb[(size_t)t * 128 + j] = __float2half(h);
        }
        if (g < 32 && t + 1 < T) xrow[g] = packh2f(xn.x, xn.y);
        __syncthreads();
    }
}

template<bool RELU>
__global__ __launch_bounds__(512)
void k_fc128(const __half* __restrict__ in16, const float* __restrict__ Wg,
             const float* __restrict__ bias, __half* __restrict__ out16, int rows)
{
    __shared__ __align__(16) unsigned rowbuf[4 * 64];
    const int tid = threadIdx.x;
    const int n   = tid & 127;
    const int rs  = tid >> 7;
    unsigned wcol[64];
#pragma unroll
    for (int k2 = 0; k2 < 64; ++k2)
        wcol[k2] = packh2f(Wg[(2*k2)*128 + n], Wg[(2*k2+1)*128 + n]);
    const float bn = bias[n];
    for (int row0 = blockIdx.x * 4; row0 < rows; row0 += gridDim.x * 4) {
        if (tid < 256)
            rowbuf[tid] = ((const unsigned*)(in16 + (size_t)row0 * 128))[tid];
        __syncthreads();
        float a0 = bn, a1 = 0.f, a2 = 0.f, a3 = 0.f;
        const uint4* hr = (const uint4*)(rowbuf + rs * 64);
#pragma unroll
        for (int k8 = 0; k8 < 16; ++k8) {
            uint4 v = hr[k8];
            a0 = fdot2u(v.x, wcol[4*k8+0], a0);
            a1 = fdot2u(v.y, wcol[4*k8+1], a1);
            a2 = fdot2u(v.z, wcol[4*k8+2], a2);
            a3 = fdot2u(v.w, wcol[4*k8+3], a3);
        }
        float a = (a0 + a1) + (a2 + a3);
        if (RELU) a = fmaxf(a, 0.f);
        out16[(size_t)(row0 + rs) * 128 + n] = __float2half(a);
        __syncthreads();
    }
}

__global__ __launch_bounds__(512)
void k_l34(const __half* __restrict__ in16, const float* __restrict__ W3,
           const float* __restrict__ b3, const float* __restrict__ W4,
           const float* __restrict__ b4, float* __restrict__ out, int rows)
{
    __shared__ __align__(16) unsigned rowbuf[16 * 64];
    __shared__ __align__(16) unsigned short d3s[16 * 32];
    const int tid = threadIdx.x;
    const int n   = tid & 31;
    const int rs  = tid >> 5;
    unsigned w3col[64];
#pragma unroll
    for (int k2 = 0; k2 < 64; ++k2)
        w3col[k2] = packh2f(W3[(2*k2)*32 + n], W3[(2*k2+1)*32 + n]);
    unsigned w4p[16];
#pragma unroll
    for (int k2 = 0; k2 < 16; ++k2)
        w4p[k2] = packh2f(W4[2*k2], W4[2*k2+1]);
    const float b3n = b3[n], b4v = b4[0];
    for (int row0 = blockIdx.x * 16; row0 < rows; row0 += gridDim.x * 16) {
        rowbuf[tid]       = ((const unsigned*)(in16 + (size_t)row0 * 128))[tid];
        rowbuf[tid + 512] = ((const unsigned*)(in16 + (size_t)row0 * 128))[tid + 512];
        __syncthreads();
        float a0 = b3n, a1 = 0.f, a2 = 0.f, a3 = 0.f;
        const uint4* hr = (const uint4*)(rowbuf + rs * 64);
#pragma unroll
        for (int k8 = 0; k8 < 16; ++k8) {
            uint4 v = hr[k8];
            a0 = fdot2u(v.x, w3col[4*k8+0], a0);
            a1 = fdot2u(v.y, w3col[4*k8+1], a1);
            a2 = fdot2u(v.z, w3col[4*k8+2], a2);
            a3 = fdot2u(v.w, w3col[4*k8+3], a3);
        }
        float a = fmaxf((a0 + a1) + (a2 + a3), 0.f);
        d3s[rs * 32 + n] = __half_as_ushort(__float2half(a));
        __syncthreads();
        if (tid < 16) {
            const uint4* dp = (const uint4*)(d3s + tid * 32);
            float s0 = b4v, s1 = 0.f;
#pragma unroll
            for (int qq = 0; qq < 4; ++qq) {
                uint4 v = dp[qq];
                s0 = fdot2u(v.x, w4p[4*qq+0], s0);
                s1 = fdot2u(v.y, w4p[4*qq+1], s1);
                s0 = fdot2u(v.z, w4p[4*qq+2], s0);
                s1 = fdot2u(v.w, w4p[4*qq+3], s1);
            }
            out[row0 + tid] = sigmoidf_fast(s0 + s1);
        }
        __syncthreads();
    }
}

// ---------------------------------------------------------------------------
extern "C" void kernel_launch(void* const* d_in, const int* in_sizes, int n_in,
                              void* d_out, int out_size, void* d_ws, size_t ws_size,
                              hipStream_t stream)
{
    const float* x  = (const float*)d_in[0];
    const float* W  = (const float*)d_in[1];
    const float* U  = (const float*)d_in[2];
    const float* b  = (const float*)d_in[3];
    const float* W1 = (const float*)d_in[4];
    const float* b1 = (const float*)d_in[5];
    const float* W2 = (const float*)d_in[6];
    const float* b2 = (const float*)d_in[7];
    const float* W3 = (const float*)d_in[8];
    const float* b3 = (const float*)d_in[9];
    const float* W4 = (const float*)d_in[10];
    const float* b4 = (const float*)d_in[11];
    float* out = (float*)d_out;

    const int T    = 2048;
    const int rows = in_sizes[0] / 64;     // B*T
    const int B    = rows / T;             // 64

    char* ws = (char*)d_ws;
    const size_t xp_bytes = (size_t)rows * 512 * sizeof(__half);   // 128 MiB
    const size_t hs_bytes = (size_t)rows * 128 * sizeof(__half);   //  32 MiB

    if (ws_size >= xp_bytes + hs_bytes) {
        __half* xpT  = (__half*)ws;
        __half* hs16 = (__half*)(ws + xp_bytes);
        k_xprojT<<<B * 4, 512, 0, stream>>>(x, W, b, xpT, B, T);
        k_lstm10<<<B, 512, 0, stream>>>(U, xpT, hs16, T);
        k_head<<<B * 32, 512, 0, stream>>>(hs16, W1, b1, W2, b2, W3, b3,
                                           W4, b4, out, T);
    } else {
        __half* hs16 = (__half*)ws;
        __half* d1   = (__half*)(ws + hs_bytes);
        __half* d2   = (__half*)ws;   // alias hs (dead after fc1)
        k_lstm_fused<<<B, 512, 0, stream>>>(U, x, W, b, hs16, T);
        k_fc128<false><<<1024, 512, 0, stream>>>(hs16, W1, b1, d1, rows);
        k_fc128<true ><<<1024, 512, 0, stream>>>(d1,  W2, b2, d2, rows);
        k_l34<<<1024, 512, 0, stream>>>(d2, W3, b3, W4, b4, out, rows);
    }
}

// Round 11
// 779.588 us; speedup vs baseline: 1.4023x; 1.0793x over previous
//
#include <hip/hip_runtime.h>
#include <hip/hip_fp16.h>
#include <cstdint>
#include <cstddef>

// ---------------------------------------------------------------------------
// helpers
// ---------------------------------------------------------------------------
typedef _Float16 hh2   __attribute__((ext_vector_type(2)));
typedef _Float16 f16x8 __attribute__((ext_vector_type(8)));
typedef float    f32x4 __attribute__((ext_vector_type(4)));
typedef int      i32x4 __attribute__((ext_vector_type(4)));

__device__ __forceinline__ float fdot2u(unsigned a, unsigned b, float c) {
#if __has_builtin(__builtin_amdgcn_fdot2)
    return __builtin_amdgcn_fdot2(__builtin_bit_cast(hh2, a),
                                  __builtin_bit_cast(hh2, b), c, false);
#else
    float r;
    asm("v_dot2_f32_f16 %0, %1, %2, %3" : "=v"(r) : "v"(a), "v"(b), "v"(c));
    return r;
#endif
}

__device__ __forceinline__ unsigned packh2f(float x, float y) {
    hh2 v; v.x = (_Float16)x; v.y = (_Float16)y;
    return __builtin_bit_cast(unsigned, v);
}

__device__ __forceinline__ float ex2(float x) {
#if __has_builtin(__builtin_amdgcn_exp2f)
    return __builtin_amdgcn_exp2f(x);
#else
    return exp2f(x);
#endif
}
__device__ __forceinline__ float sig2(float x) {
    return __builtin_amdgcn_rcpf(1.f + ex2(x * -1.442695041f));
}
__device__ __forceinline__ float tanh2(float x) {
    return fmaf(2.f, __builtin_amdgcn_rcpf(1.f + ex2(x * -2.885390082f)), -1.f);
}
__device__ __forceinline__ float sigmoidf_fast(float x) {
    return __builtin_amdgcn_rcpf(1.f + __expf(-x));
}
__device__ __forceinline__ float tanhf_fast(float x) {
    float e = __expf(-2.f * fmaxf(x, -30.f));
    return (1.f - e) * __builtin_amdgcn_rcpf(1.f + e);
}

// raw barrier: drain LDS only, keep global loads in flight
#define BAR_LGKM() asm volatile("s_waitcnt lgkmcnt(0)\n\ts_barrier" ::: "memory")

// ---------------------------------------------------------------------------
// Kernel A: xpT = f16(x @ W + b) in chunked-transposed layout:
//   xpT[(row/8)][col][row%8]   (each [c8][col] cell = 8 halves = 16B)
// ---------------------------------------------------------------------------
__global__ __launch_bounds__(512, 2)
void k_xprojT(const float* __restrict__ x, const float* __restrict__ W,
              const float* __restrict__ bias, __half* __restrict__ xpT,
              int B, int T)
{
    __shared__ unsigned short xst[2][16 * 64];

    const int tid = threadIdx.x;
    const int w   = tid >> 6;
    const int l   = tid & 63;
    const int lj  = l & 15;
    const int hi  = l >> 4;
    const int bb  = blockIdx.x >> 2;
    const int q   = blockIdx.x & 3;

    f16x8 Wf[4][2];
    float bc[4];
#pragma unroll
    for (int cg = 0; cg < 4; ++cg) {
        const int col = cg * 128 + w * 16 + lj;
#pragma unroll
        for (int kk = 0; kk < 2; ++kk)
#pragma unroll
            for (int j = 0; j < 8; ++j)
                Wf[cg][kk][j] = (_Float16)W[(size_t)(kk*32 + hi*8 + j) * 512 + col];
        bc[cg] = bias[col];
    }

    const int nch = (T / 4) / 16;
    const size_t rowbase = (size_t)bb * T + (size_t)q * (T / 4);

    const int srow = tid >> 5;
    const int scp  = tid & 31;

    float2 xn = *(const float2*)(x + (rowbase + srow) * 64 + scp * 2);

    for (int ch = 0; ch < nch; ++ch) {
        unsigned pk = packh2f(xn.x, xn.y);
        *(unsigned*)((char*)xst[ch & 1] +
            (((srow * 128 + scp * 4)) ^ ((srow & 7) << 4))) = pk;
        if (ch + 1 < nch)
            xn = *(const float2*)(x + (rowbase + (ch+1)*16 + srow) * 64 + scp * 2);
        BAR_LGKM();

        f16x8 Axf[2];
#pragma unroll
        for (int kk = 0; kk < 2; ++kk)
            Axf[kk] = *(const f16x8*)((char*)xst[ch & 1] +
                ((lj * 128 + kk * 64 + hi * 16) ^ ((lj & 7) << 4)));

        const size_t c8base = (rowbase + (size_t)ch * 16) >> 3;
#pragma unroll
        for (int cg = 0; cg < 4; ++cg) {
            f32x4 C = {bc[cg], bc[cg], bc[cg], bc[cg]};
            C = __builtin_amdgcn_mfma_f32_16x16x32_f16(Axf[0], Wf[cg][0], C, 0, 0, 0);
            C = __builtin_amdgcn_mfma_f32_16x16x32_f16(Axf[1], Wf[cg][1], C, 0, 0, 0);
            const int col = cg * 128 + w * 16 + lj;
            uint2 u;
            u.x = packh2f(C[0], C[1]);
            u.y = packh2f(C[2], C[3]);
            const size_t hidx = ((c8base + (hi >> 1)) * 512 + col) * 8 + (hi & 1) * 4;
            *(uint2*)((unsigned short*)xpT + hidx) = u;
        }
        BAR_LGKM();
    }
}

// ---------------------------------------------------------------------------
// Kernel B: i8-MFMA LSTM (r8 structure, best measured) + f16 ring for hs.
// One block/batch, 512 threads. Quarter hi owns GATE hi (order i,f,g,o).
// Per step/wave: 2 ds_read_b128 (A) + 8 i8-MFMA + 1 act + LDS exchange +
// redundant c/h + 1 barrier. hs goes to a 32-slot f16 LDS ring (halves
// alternate per 16-step chunk); one coalesced 4KB global store per chunk,
// issued in the MFMA shadow. No per-step global store in the serial ring.
// ---------------------------------------------------------------------------
__global__ __launch_bounds__(512, 2)
void k_lstm11(const float* __restrict__ U, const __half* __restrict__ xpT,
              __half* __restrict__ hs, int T)
{
    __shared__ unsigned char hbuf[2][128];            // h as i8, dbuf
    __shared__ float exch[512];                       // [wave][lj][gate]
    __shared__ __align__(16) unsigned short hring[32][128];  // f16 hs ring 8KB

    const int tid = threadIdx.x;
    const int w   = tid >> 6;
    const int l   = tid & 63;
    const int lj  = l & 15;
    const int hi  = l >> 4;
    const int bb  = blockIdx.x;

    // ---- one-time U quantization: per-column i8 B-frags (all 4 gates)
    i32x4 Bq[4][2];
    float um[4];
#pragma unroll
    for (int g = 0; g < 4; ++g) {
        const int col = g * 128 + w * 16 + lj;
        float m = 0.f;
        for (int k2 = 0; k2 < 128; ++k2)
            m = fmaxf(m, fabsf(U[(size_t)k2 * 512 + col]));
        um[g] = m;
        const float s = (m > 0.f) ? 127.f / m : 0.f;
#pragma unroll
        for (int kk = 0; kk < 2; ++kk) {
            int wds[4];
#pragma unroll
            for (int d = 0; d < 4; ++d) {
                unsigned word = 0;
#pragma unroll
                for (int b = 0; b < 4; ++b) {
                    int qv = (int)rintf(
                        U[(size_t)(kk*64 + hi*16 + d*4 + b) * 512 + col] * s);
                    word |= (unsigned)(qv & 255) << (8 * b);
                }
                wds[d] = (int)word;
            }
            Bq[g][kk] = (i32x4){wds[0], wds[1], wds[2], wds[3]};
        }
    }

    // per-lane gate constants (my gate = hi; order i,f,g,o; gate 2 = tanh)
    const float um_me = (hi & 2) ? ((hi & 1) ? um[3] : um[2])
                                 : ((hi & 1) ? um[1] : um[0]);
    const float dq_me = um_me * (1.f / (127.f * 127.f));
    const float mlt = (hi == 2) ? -2.885390082f : -1.442695041f;
    const float pa  = (hi == 2) ? 2.f : 1.f;
    const float pb  = (hi == 2) ? -1.f : 0.f;

    if (tid < 32) ((unsigned*)hbuf[0])[tid] = 0u;

    // xp prefetch: my (gate,col), one 16B cell per 8 steps
    const uint4* __restrict__ xb = (const uint4*)xpT;
    const size_t xrow = (size_t)bb * (T / 8) * 512;
    const int col_me = hi * 128 + w * 16 + lj;

    uint4 qA = xb[xrow + 0 * 512 + col_me];
    uint4 qB = xb[xrow + 1 * 512 + col_me];

    __half* __restrict__ hsb = hs + (size_t)bb * T * 128;
    float cst = 0.f;

    float* exw = &exch[w * 64 + lj * 4 + hi];            // my write slot
    const float* exr = &exch[w * 64 + lj * 4];           // my column's 4 gates

    // persistent accumulators; elem 0 zeroed per step, elems 1-3 garbage
    i32x4 Cq[4] = {{0,0,0,0},{0,0,0,0},{0,0,0,0},{0,0,0,0}};

    __syncthreads();

    const int nbody = T / 16;
    for (int k = 0; k < nbody; ++k) {
#pragma unroll
        for (int p = 0; p < 16; ++p) {
            // ---- issue A-frag reads first (fills the latency shadow)
            const unsigned char* hrow = &hbuf[p & 1][0];
            i32x4 Aq0 = *(const i32x4*)(hrow + hi * 16);
            i32x4 Aq1 = *(const i32x4*)(hrow + 64 + hi * 16);

            // ---- shadow: coalesced hs store of chunk k-1 (4KB, once/chunk)
            if (p == 4 && k > 0) {
                uint2 v = ((const uint2*)&hring[((k - 1) & 1) * 16][0])[tid];
                *(uint2*)(hsb + (size_t)(k - 1) * 2048 + tid * 4) = v;
            }
            if (p == 8)
                qA = xb[xrow + (size_t)(2*k + 2) * 512 + col_me];

            Cq[0][0] = 0; Cq[1][0] = 0; Cq[2][0] = 0; Cq[3][0] = 0;
#pragma unroll
            for (int g = 0; g < 4; ++g) {
                Cq[g] = __builtin_amdgcn_mfma_i32_16x16x64_i8(Aq0, Bq[g][0], Cq[g], 0, 0, 0);
                Cq[g] = __builtin_amdgcn_mfma_i32_16x16x64_i8(Aq1, Bq[g][1], Cq[g], 0, 0, 0);
            }

            // select MY gate's z (quarter hi -> gate hi)
            int a01 = (hi & 1) ? Cq[1][0] : Cq[0][0];
            int a23 = (hi & 1) ? Cq[3][0] : Cq[2][0];
            int zi  = (hi & 2) ? a23 : a01;

            // xp value for my (gate,col)
            const uint4 qq = (p < 8) ? qA : qB;
            const int wsel = (p & 7) >> 1;
            unsigned uw = (wsel == 0) ? qq.x : (wsel == 1) ? qq.y
                        : (wsel == 2) ? qq.z : qq.w;
            __half2 hh = __builtin_bit_cast(__half2, uw);
            float xpf = __half2float((p & 1) ? __high2half(hh) : __low2half(hh));

            float zf = fmaf((float)zi, dq_me, xpf);

            // unified activation: sigma for gates 0,1,3; tanh for gate 2
            float e = ex2(zf * mlt);
            float a = fmaf(pa, __builtin_amdgcn_rcpf(1.f + e), pb);

            // per-wave exchange: regather (i,f,g,o) for my column
            *exw = a;
            f32x4 v = *(const f32x4*)exr;

            cst = fmaf(v[1], cst, v[0] * v[2]);     // c = f*c + i*g
            float h = v[3] * tanh2(cst);            // h = o*tanh(c)

            if (l < 16) {
                hbuf[(p & 1) ^ 1][w * 16 + lj] =
                    (unsigned char)(int)rintf(h * 127.f);
                hring[(k & 1) * 16 + p][w * 16 + lj] =
                    __half_as_ushort(__float2half(h));
            }

            if (p == 15)
                qB = xb[xrow + (size_t)(2*k + 3) * 512 + col_me];
            BAR_LGKM();
        }
    }
    // tail: store final chunk (nbody-1)
    {
        uint2 v = ((const uint2*)&hring[((nbody - 1) & 1) * 16][0])[tid];
        *(uint2*)(hsb + (size_t)(nbody - 1) * 2048 + tid * 4) = v;
    }
}

// ---------------------------------------------------------------------------
// Kernel C: dense head, wide (256 CUs). Block = (batch, chunk-group of 4).
// ---------------------------------------------------------------------------
__global__ __launch_bounds__(512, 2)
void k_head(const __half* __restrict__ hs,
            const float* __restrict__ W1, const float* __restrict__ b1,
            const float* __restrict__ W2, const float* __restrict__ b2,
            const float* __restrict__ W3, const float* __restrict__ b3,
            const float* __restrict__ W4, const float* __restrict__ b4,
            float* __restrict__ out, int T)
{
    __shared__ unsigned short hstage[16 * 128];
    __shared__ unsigned short d1buf[16 * 128];
    __shared__ unsigned short d2buf[16 * 128];
    __shared__ unsigned short d3buf[16 * 40];

    const int tid = threadIdx.x;
    const int w   = tid >> 6;
    const int l   = tid & 63;
    const int lj  = l & 15;
    const int hi  = l >> 4;
    const int bb  = blockIdx.x >> 5;
    const int ch0 = (blockIdx.x & 31) * 4;

    const int col1 = w * 16 + lj;
    const int col3 = (w & 1) * 16 + lj;

    f16x8 W1f[4], W2f[4], W3f[4];
#pragma unroll
    for (int kk = 0; kk < 4; ++kk)
#pragma unroll
        for (int j = 0; j < 8; ++j) {
            W1f[kk][j] = (_Float16)W1[(size_t)(kk*32 + hi*8 + j) * 128 + col1];
            W2f[kk][j] = (_Float16)W2[(size_t)(kk*32 + hi*8 + j) * 128 + col1];
            W3f[kk][j] = (_Float16)W3[(size_t)(kk*32 + hi*8 + j) * 32 + col3];
        }
    const float b1c = b1[col1];
    const float b2c = b2[col1];
    const float b3c = b3[col3];
    unsigned w4p[16];
#pragma unroll
    for (int k2 = 0; k2 < 16; ++k2)
        w4p[k2] = packh2f(W4[2*k2], W4[2*k2 + 1]);
    const float b4v = b4[0];

    const __half* __restrict__ hsb = hs + (size_t)bb * T * 128;
    const int srow = tid >> 5;
    const int scp  = tid & 31;

    for (int ch = ch0; ch < ch0 + 4; ++ch) {
        const int t0 = ch * 16;
        uint2 hv = *(const uint2*)(hsb + (size_t)(t0 + srow) * 128 + scp * 4);
        *(uint2*)((char*)hstage + ((srow * 256 + scp * 8) ^ ((srow & 7) << 4))) = hv;
        __syncthreads();

        f16x8 A[4];
#pragma unroll
        for (int kk = 0; kk < 4; ++kk)
            A[kk] = *(const f16x8*)((char*)hstage +
                ((lj * 256 + kk * 64 + hi * 16) ^ ((lj & 7) << 4)));
        f32x4 C1 = {b1c, b1c, b1c, b1c};
#pragma unroll
        for (int kk = 0; kk < 4; ++kk)
            C1 = __builtin_amdgcn_mfma_f32_16x16x32_f16(A[kk], W1f[kk], C1, 0, 0, 0);
#pragma unroll
        for (int r = 0; r < 4; ++r) {
            const int row = hi * 4 + r;
            *(unsigned short*)((char*)d1buf + ((row * 256 + col1 * 2) ^ ((row & 7) << 4))) =
                __half_as_ushort(__float2half(C1[r]));
        }
        __syncthreads();

#pragma unroll
        for (int kk = 0; kk < 4; ++kk)
            A[kk] = *(const f16x8*)((char*)d1buf +
                ((lj * 256 + kk * 64 + hi * 16) ^ ((lj & 7) << 4)));
        f32x4 C2 = {b2c, b2c, b2c, b2c};
#pragma unroll
        for (int kk = 0; kk < 4; ++kk)
            C2 = __builtin_amdgcn_mfma_f32_16x16x32_f16(A[kk], W2f[kk], C2, 0, 0, 0);
#pragma unroll
        for (int r = 0; r < 4; ++r) {
            const int row = hi * 4 + r;
            *(unsigned short*)((char*)d2buf + ((row * 256 + col1 * 2) ^ ((row & 7) << 4))) =
                __half_as_ushort(__float2half(fmaxf(C2[r], 0.f)));
        }
        __syncthreads();

#pragma unroll
        for (int kk = 0; kk < 4; ++kk)
            A[kk] = *(const f16x8*)((char*)d2buf +
                ((lj * 256 + kk * 64 + hi * 16) ^ ((lj & 7) << 4)));
        f32x4 C3 = {b3c, b3c, b3c, b3c};
#pragma unroll
        for (int kk = 0; kk < 4; ++kk)
            C3 = __builtin_amdgcn_mfma_f32_16x16x32_f16(A[kk], W3f[kk], C3, 0, 0, 0);
        if (w < 2) {
#pragma unroll
            for (int r = 0; r < 4; ++r) {
                const int row = hi * 4 + r;
                d3buf[row * 40 + col3] =
                    __half_as_ushort(__float2half(fmaxf(C3[r], 0.f)));
            }
        }
        __syncthreads();

        if (w == 0 && l < 16) {
            const unsigned short* dr = &d3buf[l * 40];
            float s0 = b4v, s1 = 0.f;
#pragma unroll
            for (int qq = 0; qq < 4; ++qq) {
                uint4 v = *(const uint4*)(dr + qq * 8);
                s0 = fdot2u(v.x, w4p[qq*4 + 0], s0);
                s1 = fdot2u(v.y, w4p[qq*4 + 1], s1);
                s0 = fdot2u(v.z, w4p[qq*4 + 2], s0);
                s1 = fdot2u(v.w, w4p[qq*4 + 3], s1);
            }
            out[(size_t)bb * T + t0 + l] = sigmoidf_fast(s0 + s1);
        }
        __syncthreads();
    }
}

// ---------------------------------------------------------------------------
// Fallback path (small workspace): round-1 fused dot2 LSTM + dot2 head.
// ---------------------------------------------------------------------------
__global__ __launch_bounds__(512)
void k_lstm_fused(const float* __restrict__ U, const float* __restrict__ x,
                  const float* __restrict__ W, const float* __restrict__ bias,
                  __half* __restrict__ hs, int T)
{
    __shared__ __align__(16) unsigned hbuf[64];
    __shared__ float act[512];
    __shared__ __align__(16) unsigned xrow[32];

    const int g    = threadIdx.x;
    const int bb   = blockIdx.x;
    const int j    = g & 127;
    const int gate = g >> 7;

    unsigned ucol[64];
#pragma unroll
    for (int k2 = 0; k2 < 64; ++k2)
        ucol[k2] = packh2f(U[(2*k2)*512 + g], U[(2*k2+1)*512 + g]);
    unsigned wcol[32];
#pragma unroll
    for (int k2 = 0; k2 < 32; ++k2)
        wcol[k2] = packh2f(W[(2*k2)*512 + g], W[(2*k2+1)*512 + g]);
    const float bg = bias[g];
    const float2* __restrict__ xb2 = (const float2*)(x + (size_t)bb * T * 64);
    if (g < 32) { float2 x0 = xb2[g]; xrow[g] = packh2f(x0.x, x0.y); }
    if (g < 64) hbuf[g] = 0u;
    float c = 0.f;
    __half* __restrict__ hsb = hs + (size_t)bb * T * 128;
    __syncthreads();

    for (int t = 0; t < T; ++t) {
        float2 xn = make_float2(0.f, 0.f);
        if (g < 32 && t + 1 < T) xn = xb2[(size_t)(t + 1) * 32 + g];
        float a0 = bg, a1 = 0.f, a2 = 0.f, a3 = 0.f;
        const uint4* hr = (const uint4*)hbuf;
#pragma unroll
        for (int k8 = 0; k8 < 16; ++k8) {
            uint4 v = hr[k8];
            a0 = fdot2u(v.x, ucol[4*k8+0], a0);
            a1 = fdot2u(v.y, ucol[4*k8+1], a1);
            a2 = fdot2u(v.z, ucol[4*k8+2], a2);
            a3 = fdot2u(v.w, ucol[4*k8+3], a3);
        }
        const uint4* xr = (const uint4*)xrow;
#pragma unroll
        for (int k8 = 0; k8 < 8; ++k8) {
            uint4 v = xr[k8];
            a0 = fdot2u(v.x, wcol[4*k8+0], a0);
            a1 = fdot2u(v.y, wcol[4*k8+1], a1);
            a2 = fdot2u(v.z, wcol[4*k8+2], a2);
            a3 = fdot2u(v.w, wcol[4*k8+3], a3);
        }
        float z = (a0 + a1) + (a2 + a3);
        float a = (gate == 2) ? tanhf_fast(z) : sigmoidf_fast(z);
        act[g] = a;
        __syncthreads();
        float iv = act[j], fv = act[j + 128], gv = act[j + 256], ov = act[j + 384];
        c = fmaf(fv, c, iv * gv);
        float h = ov * tanhf_fast(c);
        if (gate == 0) {
            ((unsigned short*)hbuf)[j] = __half_as_ushort(__float2half(h));
            hsb[(size_t)t * 128 + j] = __float2half(h);
        }
        if (g < 32 && t + 1 < T) xrow[g] = packh2f(xn.x, xn.y);
        __syncthreads();
    }
}

template<bool RELU>
__global__ __launch_bounds__(512)
void k_fc128(const __half* __restrict__ in16, const float* __restrict__ Wg,
             const float* __restrict__ bias, __half* __restrict__ out16, int rows)
{
    __shared__ __align__(16) unsigned rowbuf[4 * 64];
    const int tid = threadIdx.x;
    const int n   = tid & 127;
    const int rs  = tid >> 7;
    unsigned wcol[64];
#pragma unroll
    for (int k2 = 0; k2 < 64; ++k2)
        wcol[k2] = packh2f(Wg[(2*k2)*128 + n], Wg[(2*k2+1)*128 + n]);
    const float bn = bias[n];
    for (int row0 = blockIdx.x * 4; row0 < rows; row0 += gridDim.x * 4) {
        if (tid < 256)
            rowbuf[tid] = ((const unsigned*)(in16 + (size_t)row0 * 128))[tid];
        __syncthreads();
        float a0 = bn, a1 = 0.f, a2 = 0.f, a3 = 0.f;
        const uint4* hr = (const uint4*)(rowbuf + rs * 64);
#pragma unroll
        for (int k8 = 0; k8 < 16; ++k8) {
            uint4 v = hr[k8];
            a0 = fdot2u(v.x, wcol[4*k8+0], a0);
            a1 = fdot2u(v.y, wcol[4*k8+1], a1);
            a2 = fdot2u(v.z, wcol[4*k8+2], a2);
            a3 = fdot2u(v.w, wcol[4*k8+3], a3);
        }
        float a = (a0 + a1) + (a2 + a3);
        if (RELU) a = fmaxf(a, 0.f);
        out16[(size_t)(row0 + rs) * 128 + n] = __float2half(a);
        __syncthreads();
    }
}

__global__ __launch_bounds__(512)
void k_l34(const __half* __restrict__ in16, const float* __restrict__ W3,
           const float* __restrict__ b3, const float* __restrict__ W4,
           const float* __restrict__ b4, float* __restrict__ out, int rows)
{
    __shared__ __align__(16) unsigned rowbuf[16 * 64];
    __shared__ __align__(16) unsigned short d3s[16 * 32];
    const int tid = threadIdx.x;
    const int n   = tid & 31;
    const int rs  = tid >> 5;
    unsigned w3col[64];
#pragma unroll
    for (int k2 = 0; k2 < 64; ++k2)
        w3col[k2] = packh2f(W3[(2*k2)*32 + n], W3[(2*k2+1)*32 + n]);
    unsigned w4p[16];
#pragma unroll
    for (int k2 = 0; k2 < 16; ++k2)
        w4p[k2] = packh2f(W4[2*k2], W4[2*k2+1]);
    const float b3n = b3[n], b4v = b4[0];
    for (int row0 = blockIdx.x * 16; row0 < rows; row0 += gridDim.x * 16) {
        rowbuf[tid]       = ((const unsigned*)(in16 + (size_t)row0 * 128))[tid];
        rowbuf[tid + 512] = ((const unsigned*)(in16 + (size_t)row0 * 128))[tid + 512];
        __syncthreads();
        float a0 = b3n, a1 = 0.f, a2 = 0.f, a3 = 0.f;
        const uint4* hr = (const uint4*)(rowbuf + rs * 64);
#pragma unroll
        for (int k8 = 0; k8 < 16; ++k8) {
            uint4 v = hr[k8];
            a0 = fdot2u(v.x, w3col[4*k8+0], a0);
            a1 = fdot2u(v.y, w3col[4*k8+1], a1);
            a2 = fdot2u(v.z, w3col[4*k8+2], a2);
            a3 = fdot2u(v.w, w3col[4*k8+3], a3);
        }
        float a = fmaxf((a0 + a1) + (a2 + a3), 0.f);
        d3s[rs * 32 + n] = __half_as_ushort(__float2half(a));
        __syncthreads();
        if (tid < 16) {
            const uint4* dp = (const uint4*)(d3s + tid * 32);
            float s0 = b4v, s1 = 0.f;
#pragma unroll
            for (int qq = 0; qq < 4; ++qq) {
                uint4 v = dp[qq];
                s0 = fdot2u(v.x, w4p[4*qq+0], s0);
                s1 = fdot2u(v.y, w4p[4*qq+1], s1);
                s0 = fdot2u(v.z, w4p[4*qq+2], s0);
                s1 = fdot2u(v.w, w4p[4*qq+3], s1);
            }
            out[row0 + tid] = sigmoidf_fast(s0 + s1);
        }
        __syncthreads();
    }
}

// ---------------------------------------------------------------------------
extern "C" void kernel_launch(void* const* d_in, const int* in_sizes, int n_in,
                              void* d_out, int out_size, void* d_ws, size_t ws_size,
                              hipStream_t stream)
{
    const float* x  = (const float*)d_in[0];
    const float* W  = (const float*)d_in[1];
    const float* U  = (const float*)d_in[2];
    const float* b  = (const float*)d_in[3];
    const float* W1 = (const float*)d_in[4];
    const float* b1 = (const float*)d_in[5];
    const float* W2 = (const float*)d_in[6];
    const float* b2 = (const float*)d_in[7];
    const float* W3 = (const float*)d_in[8];
    const float* b3 = (const float*)d_in[9];
    const float* W4 = (const float*)d_in[10];
    const float* b4 = (const float*)d_in[11];
    float* out = (float*)d_out;

    const int T    = 2048;
    const int rows = in_sizes[0] / 64;     // B*T
    const int B    = rows / T;             // 64

    char* ws = (char*)d_ws;
    const size_t xp_bytes = (size_t)rows * 512 * sizeof(__half);   // 128 MiB
    const size_t hs_bytes = (size_t)rows * 128 * sizeof(__half);   //  32 MiB

    if (ws_size >= xp_bytes + hs_bytes) {
        __half* xpT  = (__half*)ws;
        __half* hs16 = (__half*)(ws + xp_bytes);
        k_xprojT<<<B * 4, 512, 0, stream>>>(x, W, b, xpT, B, T);
        k_lstm11<<<B, 512, 0, stream>>>(U, xpT, hs16, T);
        k_head<<<B * 32, 512, 0, stream>>>(hs16, W1, b1, W2, b2, W3, b3,
                                           W4, b4, out, T);
    } else {
        __half* hs16 = (__half*)ws;
        __half* d1   = (__half*)(ws + hs_bytes);
        __half* d2   = (__half*)ws;   // alias hs (dead after fc1)
        k_lstm_fused<<<B, 512, 0, stream>>>(U, x, W, b, hs16, T);
        k_fc128<false><<<1024, 512, 0, stream>>>(hs16, W1, b1, d1, rows);
        k_fc128<true ><<<1024, 512, 0, stream>>>(d1,  W2, b2, d2, rows);
        k_l34<<<1024, 512, 0, stream>>>(d2, W3, b3, W4, b4, out, rows);
    }
}